// Round 1
// baseline (389.969 us; speedup 1.0000x reference)
//
#include <hip/hip_runtime.h>

#define N_GENOMES 4000
#define N_SAMPLES 2048
#define N_GENES   28000
#define N_SEQS    16000
#define MAXW      16     // max genes per seq; P(exceed) ~1e-7 for Poisson(1.75) x 16000
#define GRID      2048   // 8 blocks/CU x 256 CU: fully-resident persistent grid

typedef float v4f __attribute__((ext_vector_type(4)));

// ---------------- ELL build: seq -> up to MAXW (genome, pos) pairs ----------------

__global__ void ell_scatter_k(const int* __restrict__ seq_idx,
                              const int* __restrict__ genome_idx,
                              const float* __restrict__ pos,
                              int* __restrict__ counts,
                              int2* __restrict__ ell2,
                              int* __restrict__ ctr) {
    int g = blockIdx.x * blockDim.x + threadIdx.x;
    if (g == 0) *ctr = 0;          // init work counter for main kernel (runs before it)
    if (g < N_GENES) {
        int q = seq_idx[g];
        int slot = atomicAdd(&counts[q], 1);
        if (slot < MAXW)
            ell2[q * MAXW + slot] = make_int2(genome_idx[g], __float_as_int(pos[g]));
    }
}

// ---------------- main: persistent blocks, dynamic seq-row work stealing ----------
// out[q, s] = bias[q] * sum_{g : seq_idx[g]==q} A[gi,s] * 2^(1 - pos[g]*B[gi,s])

__global__ __launch_bounds__(256, 8) void main_ell_k(
    const float* __restrict__ A, const float* __restrict__ B,
    const float* __restrict__ bias,
    const int* __restrict__ counts, const int2* __restrict__ ell2,
    int* __restrict__ ctr,
    float* __restrict__ out)
{
    const int tid = threadIdx.x;
    const int s0  = tid * 8;                    // 256 threads * 8 = 2048 samples
    __shared__ int qbuf[2];                     // double-buffered grabbed seq id

    if (tid == 0) qbuf[0] = atomicAdd(ctr, 1);
    __syncthreads();
    int q = qbuf[0];
    int slot = 0;

    while (q < N_SEQS) {
        // Grab next q immediately — its latency hides under this q's work.
        if (tid == 0) qbuf[slot ^ 1] = atomicAdd(ctr, 1);

        int cnt = counts[q];
        if (cnt > MAXW) cnt = MAXW;
        const int2* __restrict__ row = ell2 + q * MAXW;

        float acc[8];
#pragma unroll
        for (int i = 0; i < 8; ++i) acc[i] = 0.0f;

        // Batches of 4 genes: issue all 16 dwordx4 loads of a batch before any
        // consumption. Metadata loads are unconditional (always in-bounds;
        // slots >= cnt hold poison but are never used as addresses).
        for (int base = 0; base < cnt; base += 4) {   // wave-uniform trip count
            int2 mb[4];
#pragma unroll
            for (int j = 0; j < 4; ++j) mb[j] = row[base + j];

            float4 av[4][2], bv[4][2];
#pragma unroll
            for (int j = 0; j < 4; ++j) {
                if (base + j < cnt) {
                    const float4* Ar = (const float4*)(A + (size_t)mb[j].x * N_SAMPLES + s0);
                    const float4* Br = (const float4*)(B + (size_t)mb[j].x * N_SAMPLES + s0);
                    av[j][0] = Ar[0]; av[j][1] = Ar[1];
                    bv[j][0] = Br[0]; bv[j][1] = Br[1];
                }
            }
#pragma unroll
            for (int j = 0; j < 4; ++j) {
                if (base + j < cnt) {
                    const float p = __int_as_float(mb[j].y);
                    acc[0] += av[j][0].x * exp2f(1.0f - p * bv[j][0].x);
                    acc[1] += av[j][0].y * exp2f(1.0f - p * bv[j][0].y);
                    acc[2] += av[j][0].z * exp2f(1.0f - p * bv[j][0].z);
                    acc[3] += av[j][0].w * exp2f(1.0f - p * bv[j][0].w);
                    acc[4] += av[j][1].x * exp2f(1.0f - p * bv[j][1].x);
                    acc[5] += av[j][1].y * exp2f(1.0f - p * bv[j][1].y);
                    acc[6] += av[j][1].z * exp2f(1.0f - p * bv[j][1].z);
                    acc[7] += av[j][1].w * exp2f(1.0f - p * bv[j][1].w);
                }
            }
        }

        // Non-temporal stores: out is never re-read; keep L2 for A/B reuse.
        const float bq = bias[q];
        v4f o0 = { acc[0] * bq, acc[1] * bq, acc[2] * bq, acc[3] * bq };
        v4f o1 = { acc[4] * bq, acc[5] * bq, acc[6] * bq, acc[7] * bq };
        float* op = out + (size_t)q * N_SAMPLES + s0;
        __builtin_nontemporal_store(o0, (v4f*)op);
        __builtin_nontemporal_store(o1, (v4f*)(op + 4));

        __syncthreads();            // qbuf[slot^1] written; qbuf[slot] free to reuse
        q = qbuf[slot ^ 1];
        slot ^= 1;
    }
}

// ---------------- launch ----------------

extern "C" void kernel_launch(void* const* d_in, const int* in_sizes, int n_in,
                              void* d_out, int out_size, void* d_ws, size_t ws_size,
                              hipStream_t stream) {
    const float* A          = (const float*)d_in[0];   // (4000, 2048)
    const float* B          = (const float*)d_in[1];   // (4000, 2048)
    const float* bias       = (const float*)d_in[2];   // (16000,)
    const float* pos        = (const float*)d_in[3];   // (28000,)
    const int*   genome_idx = (const int*)d_in[4];     // (28000,)
    const int*   seq_idx    = (const int*)d_in[5];     // (28000,)
    float*       out        = (float*)d_out;           // (16000, 2048)

    // ws layout: [counts: 16000 int][ell2: 16000*16 int2][ctr: 1 int]
    int*  counts = (int*)d_ws;
    int2* ell2   = (int2*)((char*)d_ws + ((N_SEQS * sizeof(int) + 15) & ~15));
    int*  ctr    = (int*)((char*)ell2 + (size_t)N_SEQS * MAXW * sizeof(int2));

    hipMemsetAsync(counts, 0, N_SEQS * sizeof(int), stream);
    ell_scatter_k<<<(N_GENES + 255) / 256, 256, 0, stream>>>(seq_idx, genome_idx, pos,
                                                             counts, ell2, ctr);
    main_ell_k<<<GRID, 256, 0, stream>>>(A, B, bias, counts, ell2, ctr, out);
}

// Round 2
// 389.885 us; speedup vs baseline: 1.0002x; 1.0002x over previous
//
#include <hip/hip_runtime.h>

#define N_GENOMES 4000
#define N_SAMPLES 2048
#define N_GENES   28000
#define N_SEQS    16000
#define MAXW      16     // max genes per seq; P(exceed) ~1e-7 for Poisson(1.75) x 16000
#define GRID      2048   // 8 blocks/CU x 256 CU: fully-resident persistent grid

// ---------------- ELL build: seq -> up to MAXW (genome, pos) pairs ----------------

__global__ void ell_scatter_k(const int* __restrict__ seq_idx,
                              const int* __restrict__ genome_idx,
                              const float* __restrict__ pos,
                              int* __restrict__ counts,
                              int2* __restrict__ ell2,
                              int* __restrict__ ctr) {
    int g = blockIdx.x * blockDim.x + threadIdx.x;
    if (g == 0) *ctr = 0;          // init work counter for main kernel (runs before it)
    if (g < N_GENES) {
        int q = seq_idx[g];
        int slot = atomicAdd(&counts[q], 1);
        if (slot < MAXW)
            ell2[q * MAXW + slot] = make_int2(genome_idx[g], __float_as_int(pos[g]));
    }
}

// ---------------- main: persistent blocks, dynamic seq-row work stealing ----------
// out[q, s] = bias[q] * sum_{g : seq_idx[g]==q} A[gi,s] * 2^(1 - pos[g]*B[gi,s])

__global__ __launch_bounds__(256, 8) void main_ell_k(
    const float* __restrict__ A, const float* __restrict__ B,
    const float* __restrict__ bias,
    const int* __restrict__ counts, const int2* __restrict__ ell2,
    int* __restrict__ ctr,
    float* __restrict__ out)
{
    const int tid = threadIdx.x;
    const int s0  = tid * 8;                    // 256 threads * 8 = 2048 samples
    __shared__ int qbuf[2];                     // double-buffered grabbed seq id

    if (tid == 0) qbuf[0] = atomicAdd(ctr, 1);
    __syncthreads();
    int q = qbuf[0];
    int slot = 0;

    while (q < N_SEQS) {
        // Grab next q immediately — its latency hides under this q's work.
        if (tid == 0) qbuf[slot ^ 1] = atomicAdd(ctr, 1);

        int cnt = counts[q];
        if (cnt > MAXW) cnt = MAXW;
        const int2* __restrict__ row = ell2 + q * MAXW;

        float acc[8];
#pragma unroll
        for (int i = 0; i < 8; ++i) acc[i] = 0.0f;

        // Batches of 4 genes: issue all 16 dwordx4 loads of a batch before any
        // consumption. Metadata loads are unconditional (always in-bounds;
        // slots >= cnt hold poison but are never used as addresses).
        for (int base = 0; base < cnt; base += 4) {   // wave-uniform trip count
            int2 mb[4];
#pragma unroll
            for (int j = 0; j < 4; ++j) mb[j] = row[base + j];

            float4 av[4][2], bv[4][2];
#pragma unroll
            for (int j = 0; j < 4; ++j) {
                if (base + j < cnt) {
                    const float4* Ar = (const float4*)(A + (size_t)mb[j].x * N_SAMPLES + s0);
                    const float4* Br = (const float4*)(B + (size_t)mb[j].x * N_SAMPLES + s0);
                    av[j][0] = Ar[0]; av[j][1] = Ar[1];
                    bv[j][0] = Br[0]; bv[j][1] = Br[1];
                }
            }
#pragma unroll
            for (int j = 0; j < 4; ++j) {
                if (base + j < cnt) {
                    const float p = __int_as_float(mb[j].y);
                    acc[0] += av[j][0].x * exp2f(1.0f - p * bv[j][0].x);
                    acc[1] += av[j][0].y * exp2f(1.0f - p * bv[j][0].y);
                    acc[2] += av[j][0].z * exp2f(1.0f - p * bv[j][0].z);
                    acc[3] += av[j][0].w * exp2f(1.0f - p * bv[j][0].w);
                    acc[4] += av[j][1].x * exp2f(1.0f - p * bv[j][1].x);
                    acc[5] += av[j][1].y * exp2f(1.0f - p * bv[j][1].y);
                    acc[6] += av[j][1].z * exp2f(1.0f - p * bv[j][1].z);
                    acc[7] += av[j][1].w * exp2f(1.0f - p * bv[j][1].w);
                }
            }
        }

        // Plain write-back stores: L2 merges the 16B-stride-32B pattern into
        // full lines (round-0 evidence: WRITE_SIZE == logical out size).
        const float bq = bias[q];
        float4 o0 = make_float4(acc[0] * bq, acc[1] * bq, acc[2] * bq, acc[3] * bq);
        float4 o1 = make_float4(acc[4] * bq, acc[5] * bq, acc[6] * bq, acc[7] * bq);
        float4* Or = (float4*)(out + (size_t)q * N_SAMPLES + s0);
        Or[0] = o0;
        Or[1] = o1;

        __syncthreads();            // qbuf[slot^1] written; qbuf[slot] free to reuse
        q = qbuf[slot ^ 1];
        slot ^= 1;
    }
}

// ---------------- launch ----------------

extern "C" void kernel_launch(void* const* d_in, const int* in_sizes, int n_in,
                              void* d_out, int out_size, void* d_ws, size_t ws_size,
                              hipStream_t stream) {
    const float* A          = (const float*)d_in[0];   // (4000, 2048)
    const float* B          = (const float*)d_in[1];   // (4000, 2048)
    const float* bias       = (const float*)d_in[2];   // (16000,)
    const float* pos        = (const float*)d_in[3];   // (28000,)
    const int*   genome_idx = (const int*)d_in[4];     // (28000,)
    const int*   seq_idx    = (const int*)d_in[5];     // (28000,)
    float*       out        = (float*)d_out;           // (16000, 2048)

    // ws layout: [counts: 16000 int][ell2: 16000*16 int2][ctr: 1 int]
    int*  counts = (int*)d_ws;
    int2* ell2   = (int2*)((char*)d_ws + ((N_SEQS * sizeof(int) + 15) & ~15));
    int*  ctr    = (int*)((char*)ell2 + (size_t)N_SEQS * MAXW * sizeof(int2));

    hipMemsetAsync(counts, 0, N_SEQS * sizeof(int), stream);
    ell_scatter_k<<<(N_GENES + 255) / 256, 256, 0, stream>>>(seq_idx, genome_idx, pos,
                                                             counts, ell2, ctr);
    main_ell_k<<<GRID, 256, 0, stream>>>(A, B, bias, counts, ell2, ctr, out);
}

// Round 3
// 353.109 us; speedup vs baseline: 1.1044x; 1.1041x over previous
//
#include <hip/hip_runtime.h>

#define N_GENOMES 4000
#define N_SAMPLES 2048
#define N_GENES   28000
#define N_SEQS    16000
#define MAXW      16     // max genes per seq; P(exceed) ~1e-7 for Poisson(1.75) x 16000
#define GRID      1024   // 4 blocks/CU x 256 CU: fully-resident persistent grid

// ---------------- ELL build: seq -> up to MAXW (genome, pos) pairs ----------------

__global__ void ell_scatter_k(const int* __restrict__ seq_idx,
                              const int* __restrict__ genome_idx,
                              const float* __restrict__ pos,
                              int* __restrict__ counts,
                              int2* __restrict__ ell2,
                              int* __restrict__ ctr) {
    int g = blockIdx.x * blockDim.x + threadIdx.x;
    if (g == 0) *ctr = 0;          // init work counter for main kernel (runs before it)
    if (g < N_GENES) {
        int q = seq_idx[g];
        int slot = atomicAdd(&counts[q], 1);
        if (slot < MAXW)
            ell2[q * MAXW + slot] = make_int2(genome_idx[g], __float_as_int(pos[g]));
    }
}

// ---------------- main: persistent blocks, dynamic seq-row work stealing ----------
// out[q, s] = bias[q] * sum_{g : seq_idx[g]==q} A[gi,s] * 2^(1 - pos[g]*B[gi,s])
// __launch_bounds__(256, 4): 128-VGPR cap — room for the 16-float4 batch with
// NO scratch spills (rounds 1-2 regression: (256,8) capped VGPR at 32 -> spilled).

__global__ __launch_bounds__(256, 4) void main_ell_k(
    const float* __restrict__ A, const float* __restrict__ B,
    const float* __restrict__ bias,
    const int* __restrict__ counts, const int2* __restrict__ ell2,
    int* __restrict__ ctr,
    float* __restrict__ out)
{
    const int tid = threadIdx.x;
    const int s0  = tid * 8;                    // 256 threads * 8 = 2048 samples
    __shared__ int qbuf[2];                     // double-buffered grabbed seq id

    if (tid == 0) qbuf[0] = atomicAdd(ctr, 1);
    __syncthreads();
    int q = qbuf[0];
    int slot = 0;

    while (q < N_SEQS) {
        // Grab next q immediately — its latency hides under this q's work.
        if (tid == 0) qbuf[slot ^ 1] = atomicAdd(ctr, 1);

        int cnt = counts[q];
        if (cnt > MAXW) cnt = MAXW;
        const int2* __restrict__ row = ell2 + q * MAXW;

        float acc[8];
#pragma unroll
        for (int i = 0; i < 8; ++i) acc[i] = 0.0f;

        // Batches of 4 genes: issue all 16 dwordx4 loads of a batch before any
        // consumption. Metadata loads are unconditional (always in-bounds;
        // slots >= cnt hold poison but are never used as addresses).
        for (int base = 0; base < cnt; base += 4) {   // wave-uniform trip count
            int2 mb[4];
#pragma unroll
            for (int j = 0; j < 4; ++j) mb[j] = row[base + j];

            float4 av[4][2], bv[4][2];
#pragma unroll
            for (int j = 0; j < 4; ++j) {
                if (base + j < cnt) {
                    const float4* Ar = (const float4*)(A + (size_t)mb[j].x * N_SAMPLES + s0);
                    const float4* Br = (const float4*)(B + (size_t)mb[j].x * N_SAMPLES + s0);
                    av[j][0] = Ar[0]; av[j][1] = Ar[1];
                    bv[j][0] = Br[0]; bv[j][1] = Br[1];
                }
            }
#pragma unroll
            for (int j = 0; j < 4; ++j) {
                if (base + j < cnt) {
                    const float p = __int_as_float(mb[j].y);
                    acc[0] += av[j][0].x * exp2f(1.0f - p * bv[j][0].x);
                    acc[1] += av[j][0].y * exp2f(1.0f - p * bv[j][0].y);
                    acc[2] += av[j][0].z * exp2f(1.0f - p * bv[j][0].z);
                    acc[3] += av[j][0].w * exp2f(1.0f - p * bv[j][0].w);
                    acc[4] += av[j][1].x * exp2f(1.0f - p * bv[j][1].x);
                    acc[5] += av[j][1].y * exp2f(1.0f - p * bv[j][1].y);
                    acc[6] += av[j][1].z * exp2f(1.0f - p * bv[j][1].z);
                    acc[7] += av[j][1].w * exp2f(1.0f - p * bv[j][1].w);
                }
            }
        }

        // Plain write-back stores: L2 merges the 16B-stride-32B pattern into
        // full lines (round-0 evidence: WRITE_SIZE == logical out size).
        const float bq = bias[q];
        float4 o0 = make_float4(acc[0] * bq, acc[1] * bq, acc[2] * bq, acc[3] * bq);
        float4 o1 = make_float4(acc[4] * bq, acc[5] * bq, acc[6] * bq, acc[7] * bq);
        float4* Or = (float4*)(out + (size_t)q * N_SAMPLES + s0);
        Or[0] = o0;
        Or[1] = o1;

        __syncthreads();            // qbuf[slot^1] written; qbuf[slot] free to reuse
        q = qbuf[slot ^ 1];
        slot ^= 1;
    }
}

// ---------------- launch ----------------

extern "C" void kernel_launch(void* const* d_in, const int* in_sizes, int n_in,
                              void* d_out, int out_size, void* d_ws, size_t ws_size,
                              hipStream_t stream) {
    const float* A          = (const float*)d_in[0];   // (4000, 2048)
    const float* B          = (const float*)d_in[1];   // (4000, 2048)
    const float* bias       = (const float*)d_in[2];   // (16000,)
    const float* pos        = (const float*)d_in[3];   // (28000,)
    const int*   genome_idx = (const int*)d_in[4];     // (28000,)
    const int*   seq_idx    = (const int*)d_in[5];     // (28000,)
    float*       out        = (float*)d_out;           // (16000, 2048)

    // ws layout: [counts: 16000 int][ell2: 16000*16 int2][ctr: 1 int]
    int*  counts = (int*)d_ws;
    int2* ell2   = (int2*)((char*)d_ws + ((N_SEQS * sizeof(int) + 15) & ~15));
    int*  ctr    = (int*)((char*)ell2 + (size_t)N_SEQS * MAXW * sizeof(int2));

    hipMemsetAsync(counts, 0, N_SEQS * sizeof(int), stream);
    ell_scatter_k<<<(N_GENES + 255) / 256, 256, 0, stream>>>(seq_idx, genome_idx, pos,
                                                             counts, ell2, ctr);
    main_ell_k<<<GRID, 256, 0, stream>>>(A, B, bias, counts, ell2, ctr, out);
}

// Round 4
// 232.015 us; speedup vs baseline: 1.6808x; 1.5219x over previous
//
#include <hip/hip_runtime.h>

#define N_GENOMES 4000
#define N_SAMPLES 2048
#define N_GENES   28000
#define N_SEQS    16000
#define MAXW      16     // max genes per seq; P(exceed) ~1e-7 for Poisson(1.75) x 16000
#define GRID      2048   // static persistent grid: each block owns ~8 q's (q += GRID)

// ---------------- ELL build: seq -> up to MAXW (genome, pos) pairs ----------------

__global__ void ell_scatter_k(const int* __restrict__ seq_idx,
                              const int* __restrict__ genome_idx,
                              const float* __restrict__ pos,
                              int* __restrict__ counts,
                              int2* __restrict__ ell2) {
    int g = blockIdx.x * blockDim.x + threadIdx.x;
    if (g < N_GENES) {
        int q = seq_idx[g];
        int slot = atomicAdd(&counts[q], 1);
        if (slot < MAXW)
            ell2[q * MAXW + slot] = make_int2(genome_idx[g], __float_as_int(pos[g]));
    }
}

// ---------------- main: static persistent blocks, cross-q software pipeline ------
// out[q, s] = bias[q] * sum_{g : seq_idx[g]==q} A[gi,s] * 2^(1 - pos[g]*B[gi,s])
// No atomics, no barriers, no LDS (round-3 lesson: a contended work-queue counter
// + per-q block-wide sync serializes everything). Metadata for q+GRID is
// prefetched while q's gathers/compute are in flight, so the metadata->gather
// dependency latency is paid once per block, not once per q.

__global__ __launch_bounds__(256) void main_ell_k(
    const float* __restrict__ A, const float* __restrict__ B,
    const float* __restrict__ bias,
    const int* __restrict__ counts, const int2* __restrict__ ell2,
    float* __restrict__ out)
{
    const int tid = threadIdx.x;
    const int s0  = tid * 8;                    // 256 threads * 8 = 2048 samples

    int q = blockIdx.x;
    if (q >= N_SEQS) return;

    // Pipeline state: cnt + batch-0 metadata for the CURRENT q (prefetched).
    int  cnt_c = counts[q];
    int2 mb_c[4];
#pragma unroll
    for (int j = 0; j < 4; ++j) mb_c[j] = ell2[q * MAXW + j];

    while (true) {
        const int qn = q + GRID;

        int cnt = cnt_c > MAXW ? MAXW : cnt_c;
        int2 mb0[4];
#pragma unroll
        for (int j = 0; j < 4; ++j) mb0[j] = mb_c[j];

        // ---- issue batch-0 gathers immediately (addresses already resident) ----
        float4 av[4][2], bv[4][2];
#pragma unroll
        for (int j = 0; j < 4; ++j) {
            if (j < cnt) {
                const float4* Ar = (const float4*)(A + (size_t)mb0[j].x * N_SAMPLES + s0);
                const float4* Br = (const float4*)(B + (size_t)mb0[j].x * N_SAMPLES + s0);
                av[j][0] = Ar[0]; av[j][1] = Ar[1];
                bv[j][0] = Br[0]; bv[j][1] = Br[1];
            }
        }

        // ---- prefetch NEXT q's metadata; latency hides under the gathers ----
        if (qn < N_SEQS) {
            cnt_c = counts[qn];
#pragma unroll
            for (int j = 0; j < 4; ++j) mb_c[j] = ell2[qn * MAXW + j];
        }

        float acc[8];
#pragma unroll
        for (int i = 0; i < 8; ++i) acc[i] = 0.0f;

        // ---- consume batch 0 ----
#pragma unroll
        for (int j = 0; j < 4; ++j) {
            if (j < cnt) {
                const float p = __int_as_float(mb0[j].y);
                acc[0] += av[j][0].x * exp2f(1.0f - p * bv[j][0].x);
                acc[1] += av[j][0].y * exp2f(1.0f - p * bv[j][0].y);
                acc[2] += av[j][0].z * exp2f(1.0f - p * bv[j][0].z);
                acc[3] += av[j][0].w * exp2f(1.0f - p * bv[j][0].w);
                acc[4] += av[j][1].x * exp2f(1.0f - p * bv[j][1].x);
                acc[5] += av[j][1].y * exp2f(1.0f - p * bv[j][1].y);
                acc[6] += av[j][1].z * exp2f(1.0f - p * bv[j][1].z);
                acc[7] += av[j][1].w * exp2f(1.0f - p * bv[j][1].w);
            }
        }

        // ---- rare tail (cnt > 4): 3.4% of q's; load metadata on demand ----
        for (int base = 4; base < cnt; base += 4) {
            int2 mb[4];
#pragma unroll
            for (int j = 0; j < 4; ++j) mb[j] = ell2[q * MAXW + base + j];
            float4 tav[4][2], tbv[4][2];
#pragma unroll
            for (int j = 0; j < 4; ++j) {
                if (base + j < cnt) {
                    const float4* Ar = (const float4*)(A + (size_t)mb[j].x * N_SAMPLES + s0);
                    const float4* Br = (const float4*)(B + (size_t)mb[j].x * N_SAMPLES + s0);
                    tav[j][0] = Ar[0]; tav[j][1] = Ar[1];
                    tbv[j][0] = Br[0]; tbv[j][1] = Br[1];
                }
            }
#pragma unroll
            for (int j = 0; j < 4; ++j) {
                if (base + j < cnt) {
                    const float p = __int_as_float(mb[j].y);
                    acc[0] += tav[j][0].x * exp2f(1.0f - p * tbv[j][0].x);
                    acc[1] += tav[j][0].y * exp2f(1.0f - p * tbv[j][0].y);
                    acc[2] += tav[j][0].z * exp2f(1.0f - p * tbv[j][0].z);
                    acc[3] += tav[j][0].w * exp2f(1.0f - p * tbv[j][0].w);
                    acc[4] += tav[j][1].x * exp2f(1.0f - p * tbv[j][1].x);
                    acc[5] += tav[j][1].y * exp2f(1.0f - p * tbv[j][1].y);
                    acc[6] += tav[j][1].z * exp2f(1.0f - p * tbv[j][1].z);
                    acc[7] += tav[j][1].w * exp2f(1.0f - p * tbv[j][1].w);
                }
            }
        }

        // ---- epilogue for q ----
        const float bq = bias[q];
        float4 o0 = make_float4(acc[0] * bq, acc[1] * bq, acc[2] * bq, acc[3] * bq);
        float4 o1 = make_float4(acc[4] * bq, acc[5] * bq, acc[6] * bq, acc[7] * bq);
        float4* Or = (float4*)(out + (size_t)q * N_SAMPLES + s0);
        Or[0] = o0;
        Or[1] = o1;

        if (qn >= N_SEQS) break;
        q = qn;
    }
}

// ---------------- launch ----------------

extern "C" void kernel_launch(void* const* d_in, const int* in_sizes, int n_in,
                              void* d_out, int out_size, void* d_ws, size_t ws_size,
                              hipStream_t stream) {
    const float* A          = (const float*)d_in[0];   // (4000, 2048)
    const float* B          = (const float*)d_in[1];   // (4000, 2048)
    const float* bias       = (const float*)d_in[2];   // (16000,)
    const float* pos        = (const float*)d_in[3];   // (28000,)
    const int*   genome_idx = (const int*)d_in[4];     // (28000,)
    const int*   seq_idx    = (const int*)d_in[5];     // (28000,)
    float*       out        = (float*)d_out;           // (16000, 2048)

    // ws layout: [counts: 16000 int][ell2: 16000*16 int2]
    int*  counts = (int*)d_ws;
    int2* ell2   = (int2*)((char*)d_ws + ((N_SEQS * sizeof(int) + 15) & ~15));

    hipMemsetAsync(counts, 0, N_SEQS * sizeof(int), stream);
    ell_scatter_k<<<(N_GENES + 255) / 256, 256, 0, stream>>>(seq_idx, genome_idx, pos,
                                                             counts, ell2);
    main_ell_k<<<GRID, 256, 0, stream>>>(A, B, bias, counts, ell2, out);
}